// Round 1
// baseline (356.930 us; speedup 1.0000x reference)
//
#include <hip/hip_runtime.h>

// MHA forward: B=4, S=2048, H=16, DH=64, DM=1024. fp32 in/out, bf16 MFMA internally.
// Pipeline: cast -> QKV GEMM (writes Q,K + V-transposed) -> flash attention -> out GEMM.

#define DEV __device__ __forceinline__

typedef __attribute__((ext_vector_type(8))) __bf16 bf16x8;
typedef __attribute__((ext_vector_type(4))) float f32x4;
typedef unsigned short u16;

struct alignas(8) U16x4 { u16 x, y, z, w; };

DEV u16 f2bf(float f) {
  unsigned int u = __builtin_bit_cast(unsigned int, f);
  u = u + 0x7FFFu + ((u >> 16) & 1u);   // RNE; inputs are finite
  return (u16)(u >> 16);
}

DEV void gload_lds16(const void* g, void* l) {
  // 16B direct global->LDS. LDS dest is wave-uniform base + lane*16.
  __builtin_amdgcn_global_load_lds(
      (const __attribute__((address_space(1))) unsigned int*)g,
      (__attribute__((address_space(3))) unsigned int*)l, 16, 0, 0);
}

// ---------------- cast f32 -> bf16 (vectorized) ----------------
__global__ void cast_kernel(const float* __restrict__ in, u16* __restrict__ out, int n4) {
  int i = blockIdx.x * blockDim.x + threadIdx.x;
  if (i >= n4) return;
  const float4 v = reinterpret_cast<const float4*>(in)[i];
  U16x4 o{f2bf(v.x), f2bf(v.y), f2bf(v.z), f2bf(v.w)};
  reinterpret_cast<U16x4*>(out)[i] = o;
}

// ---------------- GEMM: C[M,N] = A[M,K] * B[N,K]^T, K=1024 ----------------
// 128x128 tile, BK=64, 256 threads (2x2 waves, each 64x64).
// LDS tiles [128 rows][64 bf16] with XOR swizzle: 16B slot p = c ^ (r&7).
// MODE 0: C0 = float [M][N].
// MODE 1: QKV split: col<2048 -> qkv[row][col] bf16; col>=2048 -> V^T into vtp[b,h,e,s].
template <int MODE>
__global__ __launch_bounds__(256) void gemm_bt(
    const u16* __restrict__ A, const u16* __restrict__ B,
    void* __restrict__ C0, u16* __restrict__ vtp, int N) {
  constexpr int K = 1024;
  const int bm = blockIdx.y, bn = blockIdx.x;
  const int tid = threadIdx.x;
  const int w = tid >> 6, lane = tid & 63, lo = lane & 15, hi = lane >> 4;
  const int wm = w >> 1, wn = w & 1;

  __shared__ char lds[65536];
  char* sA = lds;            // 2 x 16KB
  char* sB = lds + 32768;    // 2 x 16KB

  const u16* Ag = A + (size_t)(bm * 128) * K;
  const u16* Bg = B + (size_t)(bn * 128) * K;

  f32x4 acc[4][4] = {};

  auto stage = [&](int buf, int k0) {
#pragma unroll
    for (int it = 0; it < 4; ++it) {
      const int L = (it * 4 + w) * 64 + lane;       // 16B slot index
      const int r = L >> 3, p = L & 7, c = p ^ (r & 7);  // pre-swizzled source
      gload_lds16(Ag + (size_t)r * K + k0 + c * 8, sA + buf * 16384 + (it * 4 + w) * 1024);
      gload_lds16(Bg + (size_t)r * K + k0 + c * 8, sB + buf * 16384 + (it * 4 + w) * 1024);
    }
  };

  stage(0, 0);
  __syncthreads();
  int cur = 0;
  for (int t = 0; t < 16; ++t) {
    if (t + 1 < 16) stage(cur ^ 1, (t + 1) * 64);
#pragma unroll
    for (int kc = 0; kc < 2; ++kc) {
      bf16x8 af[4], bfr[4];
#pragma unroll
      for (int m = 0; m < 4; ++m) {
        const int r = wm * 64 + m * 16 + lo;
        const int p = (kc * 4 + hi) ^ (r & 7);
        af[m] = *reinterpret_cast<const bf16x8*>(sA + cur * 16384 + r * 128 + p * 16);
      }
#pragma unroll
      for (int n = 0; n < 4; ++n) {
        const int r = wn * 64 + n * 16 + lo;
        const int p = (kc * 4 + hi) ^ (r & 7);
        bfr[n] = *reinterpret_cast<const bf16x8*>(sB + cur * 16384 + r * 128 + p * 16);
      }
#pragma unroll
      for (int m = 0; m < 4; ++m)
#pragma unroll
        for (int n = 0; n < 4; ++n)
          acc[m][n] = __builtin_amdgcn_mfma_f32_16x16x32_bf16(af[m], bfr[n], acc[m][n], 0, 0, 0);
    }
    __syncthreads();
    cur ^= 1;
  }

  // Epilogue. C/D layout: col = lane&15, row = (lane>>4)*4 + reg.
  const int colW = bn * 128 + wn * 64;
  const int rowW = bm * 128 + wm * 64;
  if (MODE == 0) {
    float* C = (float*)C0;
#pragma unroll
    for (int m = 0; m < 4; ++m)
#pragma unroll
      for (int n = 0; n < 4; ++n) {
        const int col = colW + n * 16 + lo;
        const int rb = rowW + m * 16 + hi * 4;
#pragma unroll
        for (int rg = 0; rg < 4; ++rg)
          C[(size_t)(rb + rg) * N + col] = acc[m][n][rg];
      }
  } else {
    u16* qkvp = (u16*)C0;
    if (bn * 128 < 2048) {          // Q or K region (block-uniform)
#pragma unroll
      for (int m = 0; m < 4; ++m)
#pragma unroll
        for (int n = 0; n < 4; ++n) {
          const int col = colW + n * 16 + lo;
          const int rb = rowW + m * 16 + hi * 4;
#pragma unroll
          for (int rg = 0; rg < 4; ++rg)
            qkvp[(size_t)(rb + rg) * 2048 + col] = f2bf(acc[m][n][rg]);
        }
    } else {                        // V region -> transposed vt[b,h,e,s]
#pragma unroll
      for (int m = 0; m < 4; ++m)
#pragma unroll
        for (int n = 0; n < 4; ++n) {
          const int col = colW + n * 16 + lo;
          const int idx = col - 2048;
          const int hh = idx >> 6, e = idx & 63;
          const int rb = rowW + m * 16 + hi * 4;
          const int bb = rb >> 11, s = rb & 2047;
          U16x4 v4{f2bf(acc[m][n][0]), f2bf(acc[m][n][1]),
                   f2bf(acc[m][n][2]), f2bf(acc[m][n][3])};
          *reinterpret_cast<U16x4*>(vtp + ((size_t)((bb * 16 + hh) * 64 + e)) * 2048 + s) = v4;
        }
    }
  }
}

// ---------------- causal flash attention ----------------
// grid(16 q-tiles, 64 bh). 256 threads = 4 waves; each wave owns 32 q-rows.
// qkv: [8192][2048] bf16 (cols 0..1023 = Q(h,e), 1024..2047 = K(h,e))
// vt:  [64][64][2048] bf16 (bh, e, s)
// heads: [8192][1024] bf16 out
__global__ __launch_bounds__(256) void attn_kernel(
    const u16* __restrict__ qkv, const u16* __restrict__ vt, u16* __restrict__ heads) {
  const int qt = blockIdx.x;   // 0..15
  const int bh = blockIdx.y;   // 0..63
  const int b = bh >> 4, h = bh & 15;
  const int tid = threadIdx.x;
  const int w = tid >> 6, lane = tid & 63, lo = lane & 15, hi = lane >> 4;

  __shared__ char lds[49152];
  char* sQP = lds;           // 16KB: Q [128][64] swz, later per-wave P tiles
  char* sK = lds + 16384;    // 2 x 8KB
  char* sV = lds + 32768;    // 2 x 8KB (V^T tiles: rows e, cols s)

  const u16* Qg = qkv + (size_t)(b * 2048 + qt * 128) * 2048 + h * 64;
  const u16* Kg = qkv + (size_t)(b * 2048) * 2048 + 1024 + h * 64;
  const u16* Vg = vt + (size_t)bh * 64 * 2048;

  // stage Q tile [128][64]
#pragma unroll
  for (int it = 0; it < 4; ++it) {
    const int L = (it * 4 + w) * 64 + lane;
    const int r = L >> 3, p = L & 7, c = p ^ (r & 7);
    gload_lds16(Qg + (size_t)r * 2048 + c * 8, sQP + (it * 4 + w) * 1024);
  }
  auto stageKV = [&](int buf, int kv0) {
#pragma unroll
    for (int it = 0; it < 2; ++it) {
      const int L = (it * 4 + w) * 64 + lane;
      const int r = L >> 3, p = L & 7, c = p ^ (r & 7);
      gload_lds16(Kg + (size_t)(kv0 + r) * 2048 + c * 8, sK + buf * 8192 + (it * 4 + w) * 1024);
      gload_lds16(Vg + (size_t)r * 2048 + kv0 + c * 8, sV + buf * 8192 + (it * 4 + w) * 1024);
    }
  };
  stageKV(0, 0);
  __syncthreads();

  bf16x8 qf[2][2];
#pragma unroll
  for (int m = 0; m < 2; ++m)
#pragma unroll
    for (int kc = 0; kc < 2; ++kc) {
      const int r = w * 32 + m * 16 + lo;
      const int p = (kc * 4 + hi) ^ (r & 7);
      qf[m][kc] = *reinterpret_cast<const bf16x8*>(sQP + r * 128 + p * 16);
    }
  __syncthreads();   // Q consumed; sQP now reusable as per-wave P storage

  float mrow[2][4], lrow[2][4];
  f32x4 oacc[2][4] = {};
#pragma unroll
  for (int m = 0; m < 2; ++m)
#pragma unroll
    for (int rg = 0; rg < 4; ++rg) { mrow[m][rg] = -1e30f; lrow[m][rg] = 0.f; }

  const int nt = 2 * (qt + 1);
  int cur = 0;
  for (int t = 0; t < nt; ++t) {
    if (t + 1 < nt) stageKV(cur ^ 1, (t + 1) * 64);

    // S = Q K^T  (S row=q via (hi,reg), col=kpos via lo)
    f32x4 sa[2][4] = {};
#pragma unroll
    for (int kc = 0; kc < 2; ++kc) {
      bf16x8 kf[4];
#pragma unroll
      for (int n = 0; n < 4; ++n) {
        const int r = n * 16 + lo;
        const int p = (kc * 4 + hi) ^ (r & 7);
        kf[n] = *reinterpret_cast<const bf16x8*>(sK + cur * 8192 + r * 128 + p * 16);
      }
#pragma unroll
      for (int m = 0; m < 2; ++m)
#pragma unroll
        for (int n = 0; n < 4; ++n)
          sa[m][n] = __builtin_amdgcn_mfma_f32_16x16x32_bf16(qf[m][kc], kf[n], sa[m][n], 0, 0, 0);
    }

    const int kv0 = t * 64;
    const bool diag = (t >= nt - 2);
    // scale + causal mask + online softmax (row stats reduced over lo lanes)
#pragma unroll
    for (int m = 0; m < 2; ++m) {
#pragma unroll
      for (int rg = 0; rg < 4; ++rg) {
        const int qrow = qt * 128 + w * 32 + m * 16 + hi * 4 + rg;
        float vals[4];
#pragma unroll
        for (int n = 0; n < 4; ++n) {
          float s = sa[m][n][rg] * 0.125f;
          if (diag && (kv0 + n * 16 + lo > qrow)) s = -1e9f;
          vals[n] = s;
        }
        float rmax = fmaxf(fmaxf(vals[0], vals[1]), fmaxf(vals[2], vals[3]));
        rmax = fmaxf(rmax, __shfl_xor(rmax, 1));
        rmax = fmaxf(rmax, __shfl_xor(rmax, 2));
        rmax = fmaxf(rmax, __shfl_xor(rmax, 4));
        rmax = fmaxf(rmax, __shfl_xor(rmax, 8));
        const float mn = fmaxf(mrow[m][rg], rmax);
        const float alpha = __expf(mrow[m][rg] - mn);
        mrow[m][rg] = mn;
        float rs = 0.f;
#pragma unroll
        for (int n = 0; n < 4; ++n) {
          const float pv = __expf(vals[n] - mn);
          sa[m][n][rg] = pv;
          rs += pv;
        }
        rs += __shfl_xor(rs, 1);
        rs += __shfl_xor(rs, 2);
        rs += __shfl_xor(rs, 4);
        rs += __shfl_xor(rs, 8);
        lrow[m][rg] = lrow[m][rg] * alpha + rs;
#pragma unroll
        for (int ne = 0; ne < 4; ++ne) oacc[m][ne][rg] *= alpha;
      }
    }

    // P (bf16) -> wave-private rows [w*32, w*32+32) of sQP, same swizzle
#pragma unroll
    for (int m = 0; m < 2; ++m)
#pragma unroll
      for (int n = 0; n < 4; ++n)
#pragma unroll
        for (int rg = 0; rg < 4; ++rg) {
          const int r = w * 32 + m * 16 + hi * 4 + rg;
          const int col = n * 16 + lo;
          const int p = (col >> 3) ^ (r & 7);
          *reinterpret_cast<u16*>(sQP + r * 128 + p * 16 + (col & 7) * 2) = f2bf(sa[m][n][rg]);
        }

    // O += P V  (A=P rows q, B=V^T rows e -> contiguous LDS reads)
#pragma unroll
    for (int kc2 = 0; kc2 < 2; ++kc2) {
      bf16x8 pf[2], vf[4];
#pragma unroll
      for (int m = 0; m < 2; ++m) {
        const int r = w * 32 + m * 16 + lo;
        const int p = (kc2 * 4 + hi) ^ (r & 7);
        pf[m] = *reinterpret_cast<const bf16x8*>(sQP + r * 128 + p * 16);
      }
#pragma unroll
      for (int ne = 0; ne < 4; ++ne) {
        const int r = ne * 16 + lo;
        const int p = (kc2 * 4 + hi) ^ (r & 7);
        vf[ne] = *reinterpret_cast<const bf16x8*>(sV + cur * 8192 + r * 128 + p * 16);
      }
#pragma unroll
      for (int m = 0; m < 2; ++m)
#pragma unroll
        for (int ne = 0; ne < 4; ++ne)
          oacc[m][ne] = __builtin_amdgcn_mfma_f32_16x16x32_bf16(pf[m], vf[ne], oacc[m][ne], 0, 0, 0);
    }
    __syncthreads();
    cur ^= 1;
  }

  // epilogue: heads[b*2048+q][h*64+e] = O/l
#pragma unroll
  for (int m = 0; m < 2; ++m)
#pragma unroll
    for (int rg = 0; rg < 4; ++rg) {
      const float inv = 1.0f / lrow[m][rg];
      const int q = qt * 128 + w * 32 + m * 16 + hi * 4 + rg;
#pragma unroll
      for (int ne = 0; ne < 4; ++ne) {
        const int col = h * 64 + ne * 16 + lo;
        heads[(size_t)(b * 2048 + q) * 1024 + col] = f2bf(oacc[m][ne][rg] * inv);
      }
    }
}

extern "C" void kernel_launch(void* const* d_in, const int* in_sizes, int n_in,
                              void* d_out, int out_size, void* d_ws, size_t ws_size,
                              hipStream_t stream) {
  const float* x  = (const float*)d_in[0];
  const float* wq = (const float*)d_in[1];
  const float* wk = (const float*)d_in[2];
  const float* wv = (const float*)d_in[3];
  const float* wo = (const float*)d_in[4];

  char* ws = (char*)d_ws;
  u16* xb    = (u16*)(ws);                 // [8192][1024]      16.78 MB
  u16* wqkvb = (u16*)(ws + 16777216);      // [3072][1024]       6.29 MB
  u16* wob   = (u16*)(ws + 23068672);      // [1024][1024]       2.10 MB
  u16* qkv   = (u16*)(ws + 25165824);      // [8192][2048]      33.55 MB
  u16* vtp   = (u16*)(ws + 58720256);      // [64][64][2048]    16.78 MB
  u16* heads = (u16*)(ws + 75497472);      // [8192][1024]      16.78 MB
  // total 92.3 MB

  cast_kernel<<<8192, 256, 0, stream>>>(x, xb, 2097152);
  cast_kernel<<<1024, 256, 0, stream>>>(wq, wqkvb, 262144);
  cast_kernel<<<1024, 256, 0, stream>>>(wk, wqkvb + 1048576, 262144);
  cast_kernel<<<1024, 256, 0, stream>>>(wv, wqkvb + 2097152, 262144);
  cast_kernel<<<1024, 256, 0, stream>>>(wo, wob, 262144);

  gemm_bt<1><<<dim3(24, 64), 256, 0, stream>>>(xb, wqkvb, qkv, vtp, 3072);
  attn_kernel<<<dim3(16, 64), 256, 0, stream>>>(qkv, vtp, heads);
  gemm_bt<0><<<dim3(8, 64), 256, 0, stream>>>(heads, wob, d_out, nullptr, 1024);
}

// Round 2
// 249.705 us; speedup vs baseline: 1.4294x; 1.4294x over previous
//
#include <hip/hip_runtime.h>

// MHA forward: B=4, S=2048, H=16, DH=64, DM=1024. fp32 in/out, bf16 MFMA internally.
// Pipeline: cast -> QKV GEMM (writes Q*0.125*log2e, K, V-transposed) -> flash attention -> out GEMM.

#define DEV __device__ __forceinline__

typedef __attribute__((ext_vector_type(8))) __bf16 bf16x8;
typedef __attribute__((ext_vector_type(4))) float f32x4;
typedef unsigned short u16;

struct alignas(8) U16x4 { u16 x, y, z, w; };

DEV u16 f2bf(float f) {
  unsigned int u = __builtin_bit_cast(unsigned int, f);
  u = u + 0x7FFFu + ((u >> 16) & 1u);   // RNE; inputs are finite
  return (u16)(u >> 16);
}

DEV void gload_lds16(const void* g, void* l) {
  // 16B direct global->LDS. LDS dest is wave-uniform base + lane*16.
  __builtin_amdgcn_global_load_lds(
      (const __attribute__((address_space(1))) unsigned int*)g,
      (__attribute__((address_space(3))) unsigned int*)l, 16, 0, 0);
}

// ---------------- cast f32 -> bf16 (vectorized) ----------------
__global__ void cast_kernel(const float* __restrict__ in, u16* __restrict__ out, int n4) {
  int i = blockIdx.x * blockDim.x + threadIdx.x;
  if (i >= n4) return;
  const float4 v = reinterpret_cast<const float4*>(in)[i];
  U16x4 o{f2bf(v.x), f2bf(v.y), f2bf(v.z), f2bf(v.w)};
  reinterpret_cast<U16x4*>(out)[i] = o;
}

// all 4 weight tensors in one launch: y=0..2 -> wq/wk/wv into wqkvb, y=3 -> wo into wob
__global__ void cast_w_kernel(const float* __restrict__ wq, const float* __restrict__ wk,
                              const float* __restrict__ wv, const float* __restrict__ wo,
                              u16* __restrict__ wqkvb, u16* __restrict__ wob) {
  const int y = blockIdx.y;
  const int i = blockIdx.x * blockDim.x + threadIdx.x;   // 0..262143 (float4 idx)
  const float* src = (y == 0) ? wq : (y == 1) ? wk : (y == 2) ? wv : wo;
  u16* dst = (y < 3) ? (wqkvb + (size_t)y * 1048576) : wob;
  const float4 v = reinterpret_cast<const float4*>(src)[i];
  U16x4 o{f2bf(v.x), f2bf(v.y), f2bf(v.z), f2bf(v.w)};
  reinterpret_cast<U16x4*>(dst)[i] = o;
}

// ---------------- GEMM: C[M,N] = A[M,K] * B[N,K]^T, K=1024 ----------------
// 128x128 tile, BK=64, 256 threads (2x2 waves, each 64x64).
// LDS tiles [128 rows][64 bf16] with XOR swizzle: 16B slot p = c ^ (r&7).
// MODE 0: C0 = float [M][N].
// MODE 1: QKV split: col<1024 -> Q*0.18033688 (scale+log2e folded for attention's exp2)
//         col<2048 -> K; col>=2048 -> V^T into vtp[b,h,e,s].
template <int MODE>
__global__ __launch_bounds__(256) void gemm_bt(
    const u16* __restrict__ A, const u16* __restrict__ B,
    void* __restrict__ C0, u16* __restrict__ vtp, int N) {
  constexpr int K = 1024;
  const int bm = blockIdx.y, bn = blockIdx.x;
  const int tid = threadIdx.x;
  const int w = tid >> 6, lane = tid & 63, lo = lane & 15, hi = lane >> 4;
  const int wm = w >> 1, wn = w & 1;

  __shared__ char lds[65536];
  char* sA = lds;            // 2 x 16KB
  char* sB = lds + 32768;    // 2 x 16KB

  const u16* Ag = A + (size_t)(bm * 128) * K;
  const u16* Bg = B + (size_t)(bn * 128) * K;

  f32x4 acc[4][4] = {};

  auto stage = [&](int buf, int k0) {
#pragma unroll
    for (int it = 0; it < 4; ++it) {
      const int L = (it * 4 + w) * 64 + lane;       // 16B slot index
      const int r = L >> 3, p = L & 7, c = p ^ (r & 7);  // pre-swizzled source
      gload_lds16(Ag + (size_t)r * K + k0 + c * 8, sA + buf * 16384 + (it * 4 + w) * 1024);
      gload_lds16(Bg + (size_t)r * K + k0 + c * 8, sB + buf * 16384 + (it * 4 + w) * 1024);
    }
  };

  stage(0, 0);
  __syncthreads();
  int cur = 0;
  for (int t = 0; t < 16; ++t) {
    if (t + 1 < 16) stage(cur ^ 1, (t + 1) * 64);
#pragma unroll
    for (int kc = 0; kc < 2; ++kc) {
      bf16x8 af[4], bfr[4];
#pragma unroll
      for (int m = 0; m < 4; ++m) {
        const int r = wm * 64 + m * 16 + lo;
        const int p = (kc * 4 + hi) ^ (r & 7);
        af[m] = *reinterpret_cast<const bf16x8*>(sA + cur * 16384 + r * 128 + p * 16);
      }
#pragma unroll
      for (int n = 0; n < 4; ++n) {
        const int r = wn * 64 + n * 16 + lo;
        const int p = (kc * 4 + hi) ^ (r & 7);
        bfr[n] = *reinterpret_cast<const bf16x8*>(sB + cur * 16384 + r * 128 + p * 16);
      }
#pragma unroll
      for (int m = 0; m < 4; ++m)
#pragma unroll
        for (int n = 0; n < 4; ++n)
          acc[m][n] = __builtin_amdgcn_mfma_f32_16x16x32_bf16(af[m], bfr[n], acc[m][n], 0, 0, 0);
    }
    __syncthreads();
    cur ^= 1;
  }

  // Epilogue. C/D layout: col = lane&15, row = (lane>>4)*4 + reg.
  const int colW = bn * 128 + wn * 64;
  const int rowW = bm * 128 + wm * 64;
  if (MODE == 0) {
    float* C = (float*)C0;
#pragma unroll
    for (int m = 0; m < 4; ++m)
#pragma unroll
      for (int n = 0; n < 4; ++n) {
        const int col = colW + n * 16 + lo;
        const int rb = rowW + m * 16 + hi * 4;
#pragma unroll
        for (int rg = 0; rg < 4; ++rg)
          C[(size_t)(rb + rg) * N + col] = acc[m][n][rg];
      }
  } else {
    u16* qkvp = (u16*)C0;
    if (bn * 128 < 2048) {          // Q or K region (block-uniform)
      // Q gets 0.125 (1/sqrt(64)) * log2(e) folded in so attention uses exp2 directly.
      const float qs = (bn < 8) ? 0.18033688011112042f : 1.0f;
#pragma unroll
      for (int m = 0; m < 4; ++m)
#pragma unroll
        for (int n = 0; n < 4; ++n) {
          const int col = colW + n * 16 + lo;
          const int rb = rowW + m * 16 + hi * 4;
#pragma unroll
          for (int rg = 0; rg < 4; ++rg)
            qkvp[(size_t)(rb + rg) * 2048 + col] = f2bf(acc[m][n][rg] * qs);
        }
    } else {                        // V region -> transposed vt[b,h,e,s]
#pragma unroll
      for (int m = 0; m < 4; ++m)
#pragma unroll
        for (int n = 0; n < 4; ++n) {
          const int col = colW + n * 16 + lo;
          const int idx = col - 2048;
          const int hh = idx >> 6, e = idx & 63;
          const int rb = rowW + m * 16 + hi * 4;
          const int bb = rb >> 11, s = rb & 2047;
          U16x4 v4{f2bf(acc[m][n][0]), f2bf(acc[m][n][1]),
                   f2bf(acc[m][n][2]), f2bf(acc[m][n][3])};
          *reinterpret_cast<U16x4*>(vtp + ((size_t)((bb * 16 + hh) * 64 + e)) * 2048 + s) = v4;
        }
    }
  }
}

// ---------------- causal flash attention ----------------
// grid(8 paired q-tiles, 64 bh). Each block handles q-tiles {bx, 15-bx} -> uniform
// 34 KV-steps per block (load balance: fixes the 16x work spread / 11% occupancy).
// 256 threads = 4 waves; each wave owns 32 q-rows of the 128-row tile.
// qkv: [8192][2048] bf16 (cols 0..1023 = Q(h,e) prescaled, 1024..2047 = K(h,e))
// vt:  [64][64][2048] bf16 (bh, e, s)
// heads: [8192][1024] bf16 out
__global__ __launch_bounds__(256) void attn_kernel(
    const u16* __restrict__ qkv, const u16* __restrict__ vt, u16* __restrict__ heads) {
  const int bx = blockIdx.x;   // 0..7
  const int bh = blockIdx.y;   // 0..63
  const int b = bh >> 4, h = bh & 15;
  const int tid = threadIdx.x;
  const int w = tid >> 6, lane = tid & 63, lo = lane & 15, hi = lane >> 4;

  __shared__ char lds[49152];
  char* sQP = lds;           // 16KB: Q [128][64] swz, later per-wave P tiles
  char* sK = lds + 16384;    // 2 x 8KB
  char* sV = lds + 32768;    // 2 x 8KB (V^T tiles: rows e, cols s)

  const u16* Kg = qkv + (size_t)(b * 2048) * 2048 + 1024 + h * 64;
  const u16* Vg = vt + (size_t)bh * 64 * 2048;

  auto stageKV = [&](int buf, int kv0) {
#pragma unroll
    for (int it = 0; it < 2; ++it) {
      const int L = (it * 4 + w) * 64 + lane;
      const int r = L >> 3, p = L & 7, c = p ^ (r & 7);
      gload_lds16(Kg + (size_t)(kv0 + r) * 2048 + c * 8, sK + buf * 8192 + (it * 4 + w) * 1024);
      gload_lds16(Vg + (size_t)r * 2048 + kv0 + c * 8, sV + buf * 8192 + (it * 4 + w) * 1024);
    }
  };

  for (int rep = 0; rep < 2; ++rep) {
    const int qt = (rep == 0) ? bx : 15 - bx;
    const u16* Qg = qkv + (size_t)(b * 2048 + qt * 128) * 2048 + h * 64;

    // stage Q tile [128][64]
#pragma unroll
    for (int it = 0; it < 4; ++it) {
      const int L = (it * 4 + w) * 64 + lane;
      const int r = L >> 3, p = L & 7, c = p ^ (r & 7);
      gload_lds16(Qg + (size_t)r * 2048 + c * 8, sQP + (it * 4 + w) * 1024);
    }
    stageKV(0, 0);
    __syncthreads();

    bf16x8 qf[2][2];
#pragma unroll
    for (int m = 0; m < 2; ++m)
#pragma unroll
      for (int kc = 0; kc < 2; ++kc) {
        const int r = w * 32 + m * 16 + lo;
        const int p = (kc * 4 + hi) ^ (r & 7);
        qf[m][kc] = *reinterpret_cast<const bf16x8*>(sQP + r * 128 + p * 16);
      }
    __syncthreads();   // Q consumed; sQP now reusable as per-wave P storage

    float mrow[2][4], lrow[2][4];
    f32x4 oacc[2][4] = {};
#pragma unroll
    for (int m = 0; m < 2; ++m)
#pragma unroll
      for (int rg = 0; rg < 4; ++rg) { mrow[m][rg] = -1e30f; lrow[m][rg] = 0.f; }

    const int nt = 2 * (qt + 1);
    int cur = 0;
    for (int t = 0; t < nt; ++t) {
      if (t + 1 < nt) stageKV(cur ^ 1, (t + 1) * 64);

      // S = Q K^T  (S row=q via (hi,reg), col=kpos via lo). S already in log2 domain.
      f32x4 sa[2][4] = {};
#pragma unroll
      for (int kc = 0; kc < 2; ++kc) {
        bf16x8 kf[4];
#pragma unroll
        for (int n = 0; n < 4; ++n) {
          const int r = n * 16 + lo;
          const int p = (kc * 4 + hi) ^ (r & 7);
          kf[n] = *reinterpret_cast<const bf16x8*>(sK + cur * 8192 + r * 128 + p * 16);
        }
#pragma unroll
        for (int m = 0; m < 2; ++m)
#pragma unroll
          for (int n = 0; n < 4; ++n)
            sa[m][n] = __builtin_amdgcn_mfma_f32_16x16x32_bf16(qf[m][kc], kf[n], sa[m][n], 0, 0, 0);
      }

      const int kv0 = t * 64;
      const bool diag = (t >= nt - 2);
      // causal mask + online softmax (max reduced over lo lanes; l kept per-lane partial)
#pragma unroll
      for (int m = 0; m < 2; ++m) {
#pragma unroll
        for (int rg = 0; rg < 4; ++rg) {
          const int qrow = qt * 128 + w * 32 + m * 16 + hi * 4 + rg;
          float vals[4];
#pragma unroll
          for (int n = 0; n < 4; ++n) {
            float s = sa[m][n][rg];
            if (diag && (kv0 + n * 16 + lo > qrow)) s = -1e9f;
            vals[n] = s;
          }
          float rmax = fmaxf(fmaxf(vals[0], vals[1]), fmaxf(vals[2], vals[3]));
          rmax = fmaxf(rmax, __shfl_xor(rmax, 1));
          rmax = fmaxf(rmax, __shfl_xor(rmax, 2));
          rmax = fmaxf(rmax, __shfl_xor(rmax, 4));
          rmax = fmaxf(rmax, __shfl_xor(rmax, 8));
          const float mn = fmaxf(mrow[m][rg], rmax);
          const float alpha = exp2f(mrow[m][rg] - mn);
          mrow[m][rg] = mn;
          float rs = 0.f;
#pragma unroll
          for (int n = 0; n < 4; ++n) {
            const float pv = exp2f(vals[n] - mn);
            sa[m][n][rg] = pv;
            rs += pv;
          }
          lrow[m][rg] = lrow[m][rg] * alpha + rs;   // per-lane partial; reduced at epilogue
#pragma unroll
          for (int ne = 0; ne < 4; ++ne) oacc[m][ne][rg] *= alpha;
        }
      }

      // P (bf16) -> wave-private rows [w*32, w*32+32) of sQP, same swizzle
#pragma unroll
      for (int m = 0; m < 2; ++m)
#pragma unroll
        for (int n = 0; n < 4; ++n)
#pragma unroll
          for (int rg = 0; rg < 4; ++rg) {
            const int r = w * 32 + m * 16 + hi * 4 + rg;
            const int col = n * 16 + lo;
            const int p = (col >> 3) ^ (r & 7);
            *reinterpret_cast<u16*>(sQP + r * 128 + p * 16 + (col & 7) * 2) = f2bf(sa[m][n][rg]);
          }

      // O += P V  (A=P rows q, B=V^T rows e -> contiguous LDS reads)
#pragma unroll
      for (int kc2 = 0; kc2 < 2; ++kc2) {
        bf16x8 pf[2], vf[4];
#pragma unroll
        for (int m = 0; m < 2; ++m) {
          const int r = w * 32 + m * 16 + lo;
          const int p = (kc2 * 4 + hi) ^ (r & 7);
          pf[m] = *reinterpret_cast<const bf16x8*>(sQP + r * 128 + p * 16);
        }
#pragma unroll
        for (int ne = 0; ne < 4; ++ne) {
          const int r = ne * 16 + lo;
          const int p = (kc2 * 4 + hi) ^ (r & 7);
          vf[ne] = *reinterpret_cast<const bf16x8*>(sV + cur * 8192 + r * 128 + p * 16);
        }
#pragma unroll
        for (int m = 0; m < 2; ++m)
#pragma unroll
          for (int ne = 0; ne < 4; ++ne)
            oacc[m][ne] = __builtin_amdgcn_mfma_f32_16x16x32_bf16(pf[m], vf[ne], oacc[m][ne], 0, 0, 0);
      }
      __syncthreads();
      cur ^= 1;
    }

    // epilogue: reduce per-lane l partials over lo lanes, then heads[b*2048+q][h*64+e] = O/l
#pragma unroll
    for (int m = 0; m < 2; ++m)
#pragma unroll
      for (int rg = 0; rg < 4; ++rg) {
        float lsum = lrow[m][rg];
        lsum += __shfl_xor(lsum, 1);
        lsum += __shfl_xor(lsum, 2);
        lsum += __shfl_xor(lsum, 4);
        lsum += __shfl_xor(lsum, 8);
        const float inv = 1.0f / lsum;
        const int q = qt * 128 + w * 32 + m * 16 + hi * 4 + rg;
#pragma unroll
        for (int ne = 0; ne < 4; ++ne) {
          const int col = h * 64 + ne * 16 + lo;
          heads[(size_t)(b * 2048 + q) * 1024 + col] = f2bf(oacc[m][ne][rg] * inv);
        }
      }
    // safe to proceed to next rep: last loop iteration ended with __syncthreads(),
    // and the epilogue touches only registers + global memory.
  }
}

extern "C" void kernel_launch(void* const* d_in, const int* in_sizes, int n_in,
                              void* d_out, int out_size, void* d_ws, size_t ws_size,
                              hipStream_t stream) {
  const float* x  = (const float*)d_in[0];
  const float* wq = (const float*)d_in[1];
  const float* wk = (const float*)d_in[2];
  const float* wv = (const float*)d_in[3];
  const float* wo = (const float*)d_in[4];

  char* ws = (char*)d_ws;
  u16* xb    = (u16*)(ws);                 // [8192][1024]      16.78 MB
  u16* wqkvb = (u16*)(ws + 16777216);      // [3072][1024]       6.29 MB
  u16* wob   = (u16*)(ws + 23068672);      // [1024][1024]       2.10 MB
  u16* qkv   = (u16*)(ws + 25165824);      // [8192][2048]      33.55 MB
  u16* vtp   = (u16*)(ws + 58720256);      // [64][64][2048]    16.78 MB
  u16* heads = (u16*)(ws + 75497472);      // [8192][1024]      16.78 MB
  // total 92.3 MB

  cast_kernel<<<8192, 256, 0, stream>>>(x, xb, 2097152);
  cast_w_kernel<<<dim3(1024, 4), 256, 0, stream>>>(wq, wk, wv, wo, wqkvb, wob);

  gemm_bt<1><<<dim3(24, 64), 256, 0, stream>>>(xb, wqkvb, qkv, vtp, 3072);
  attn_kernel<<<dim3(8, 64), 256, 0, stream>>>(qkv, vtp, heads);
  gemm_bt<0><<<dim3(8, 64), 256, 0, stream>>>(heads, wob, d_out, nullptr, 1024);
}

// Round 3
// 193.648 us; speedup vs baseline: 1.8432x; 1.2895x over previous
//
#include <hip/hip_runtime.h>

// MHA forward: B=4, S=2048, H=16, DH=64, DM=1024. fp32 in/out, bf16 MFMA internally.
// Pipeline: cast -> QKV GEMM (writes Q*0.125*log2e, K, V-transposed) -> flash attention -> out GEMM.

#define DEV __device__ __forceinline__

typedef __attribute__((ext_vector_type(8))) __bf16 bf16x8;
typedef __attribute__((ext_vector_type(4))) float f32x4;
typedef unsigned short u16;

struct alignas(8) U16x4 { u16 x, y, z, w; };

DEV u16 f2bf(float f) {
  unsigned int u = __builtin_bit_cast(unsigned int, f);
  u = u + 0x7FFFu + ((u >> 16) & 1u);   // RNE; inputs are finite
  return (u16)(u >> 16);
}

DEV unsigned cvt_pk_bf16(float a, float b) {   // low = a, high = b
  unsigned r;
  asm("v_cvt_pk_bf16_f32 %0, %1, %2" : "=v"(r) : "v"(a), "v"(b));
  return r;
}

DEV void gload_lds16(const void* g, void* l) {
  // 16B direct global->LDS. LDS dest is wave-uniform base + lane*16.
  __builtin_amdgcn_global_load_lds(
      (const __attribute__((address_space(1))) unsigned int*)g,
      (__attribute__((address_space(3))) unsigned int*)l, 16, 0, 0);
}

// ---------------- cast f32 -> bf16 (vectorized) ----------------
__global__ void cast_kernel(const float* __restrict__ in, u16* __restrict__ out, int n4) {
  int i = blockIdx.x * blockDim.x + threadIdx.x;
  if (i >= n4) return;
  const float4 v = reinterpret_cast<const float4*>(in)[i];
  U16x4 o{f2bf(v.x), f2bf(v.y), f2bf(v.z), f2bf(v.w)};
  reinterpret_cast<U16x4*>(out)[i] = o;
}

// all 4 weight tensors in one launch: y=0..2 -> wq/wk/wv into wqkvb, y=3 -> wo into wob
__global__ void cast_w_kernel(const float* __restrict__ wq, const float* __restrict__ wk,
                              const float* __restrict__ wv, const float* __restrict__ wo,
                              u16* __restrict__ wqkvb, u16* __restrict__ wob) {
  const int y = blockIdx.y;
  const int i = blockIdx.x * blockDim.x + threadIdx.x;   // 0..262143 (float4 idx)
  const float* src = (y == 0) ? wq : (y == 1) ? wk : (y == 2) ? wv : wo;
  u16* dst = (y < 3) ? (wqkvb + (size_t)y * 1048576) : wob;
  const float4 v = reinterpret_cast<const float4*>(src)[i];
  U16x4 o{f2bf(v.x), f2bf(v.y), f2bf(v.z), f2bf(v.w)};
  reinterpret_cast<U16x4*>(dst)[i] = o;
}

// ---------------- GEMM: C[M,N] = A[M,K] * B[N,K]^T, K=1024 ----------------
// 128x128 tile, BK=64, 256 threads (2x2 waves, each 64x64).
// LDS tiles [128 rows][64 bf16] with XOR swizzle: 16B slot p = c ^ (r&7).
// MODE 0: C0 = float [M][N].
// MODE 1: QKV split: col<1024 -> Q*0.18033688 (scale+log2e folded for attention's exp2)
//         col<2048 -> K; col>=2048 -> V^T into vtp[b,h,e,s].
template <int MODE>
__global__ __launch_bounds__(256) void gemm_bt(
    const u16* __restrict__ A, const u16* __restrict__ B,
    void* __restrict__ C0, u16* __restrict__ vtp, int N) {
  constexpr int K = 1024;
  const int bm = blockIdx.y, bn = blockIdx.x;
  const int tid = threadIdx.x;
  const int w = tid >> 6, lane = tid & 63, lo = lane & 15, hi = lane >> 4;
  const int wm = w >> 1, wn = w & 1;

  __shared__ char lds[65536];
  char* sA = lds;            // 2 x 16KB
  char* sB = lds + 32768;    // 2 x 16KB

  const u16* Ag = A + (size_t)(bm * 128) * K;
  const u16* Bg = B + (size_t)(bn * 128) * K;

  f32x4 acc[4][4] = {};

  auto stage = [&](int buf, int k0) {
#pragma unroll
    for (int it = 0; it < 4; ++it) {
      const int L = (it * 4 + w) * 64 + lane;       // 16B slot index
      const int r = L >> 3, p = L & 7, c = p ^ (r & 7);  // pre-swizzled source
      gload_lds16(Ag + (size_t)r * K + k0 + c * 8, sA + buf * 16384 + (it * 4 + w) * 1024);
      gload_lds16(Bg + (size_t)r * K + k0 + c * 8, sB + buf * 16384 + (it * 4 + w) * 1024);
    }
  };

  stage(0, 0);
  __syncthreads();
  int cur = 0;
  for (int t = 0; t < 16; ++t) {
    if (t + 1 < 16) stage(cur ^ 1, (t + 1) * 64);
#pragma unroll
    for (int kc = 0; kc < 2; ++kc) {
      bf16x8 af[4], bfr[4];
#pragma unroll
      for (int m = 0; m < 4; ++m) {
        const int r = wm * 64 + m * 16 + lo;
        const int p = (kc * 4 + hi) ^ (r & 7);
        af[m] = *reinterpret_cast<const bf16x8*>(sA + cur * 16384 + r * 128 + p * 16);
      }
#pragma unroll
      for (int n = 0; n < 4; ++n) {
        const int r = wn * 64 + n * 16 + lo;
        const int p = (kc * 4 + hi) ^ (r & 7);
        bfr[n] = *reinterpret_cast<const bf16x8*>(sB + cur * 16384 + r * 128 + p * 16);
      }
#pragma unroll
      for (int m = 0; m < 4; ++m)
#pragma unroll
        for (int n = 0; n < 4; ++n)
          acc[m][n] = __builtin_amdgcn_mfma_f32_16x16x32_bf16(af[m], bfr[n], acc[m][n], 0, 0, 0);
    }
    __syncthreads();
    cur ^= 1;
  }

  // Epilogue. C/D layout: col = lane&15, row = (lane>>4)*4 + reg.
  const int colW = bn * 128 + wn * 64;
  const int rowW = bm * 128 + wm * 64;
  if (MODE == 0) {
    float* C = (float*)C0;
#pragma unroll
    for (int m = 0; m < 4; ++m)
#pragma unroll
      for (int n = 0; n < 4; ++n) {
        const int col = colW + n * 16 + lo;
        const int rb = rowW + m * 16 + hi * 4;
#pragma unroll
        for (int rg = 0; rg < 4; ++rg)
          C[(size_t)(rb + rg) * N + col] = acc[m][n][rg];
      }
  } else {
    u16* qkvp = (u16*)C0;
    if (bn * 128 < 2048) {          // Q or K region (block-uniform)
      // Q gets 0.125 (1/sqrt(64)) * log2(e) folded in so attention uses exp2 directly.
      const float qs = (bn < 8) ? 0.18033688011112042f : 1.0f;
#pragma unroll
      for (int m = 0; m < 4; ++m)
#pragma unroll
        for (int n = 0; n < 4; ++n) {
          const int col = colW + n * 16 + lo;
          const int rb = rowW + m * 16 + hi * 4;
#pragma unroll
          for (int rg = 0; rg < 4; ++rg)
            qkvp[(size_t)(rb + rg) * 2048 + col] = f2bf(acc[m][n][rg] * qs);
        }
    } else {                        // V region -> transposed vt[b,h,e,s]
#pragma unroll
      for (int m = 0; m < 4; ++m)
#pragma unroll
        for (int n = 0; n < 4; ++n) {
          const int col = colW + n * 16 + lo;
          const int idx = col - 2048;
          const int hh = idx >> 6, e = idx & 63;
          const int rb = rowW + m * 16 + hi * 4;
          const int bb = rb >> 11, s = rb & 2047;
          U16x4 v4{f2bf(acc[m][n][0]), f2bf(acc[m][n][1]),
                   f2bf(acc[m][n][2]), f2bf(acc[m][n][3])};
          *reinterpret_cast<U16x4*>(vtp + ((size_t)((bb * 16 + hh) * 64 + e)) * 2048 + s) = v4;
        }
    }
  }
}

// ---------------- causal flash attention (swapped-operand, in-register softmax) ----------------
// grid(16, 64): block handles q-tiles {bx, 31-bx} of 64 rows -> uniform 33 KV64-steps.
// 256 threads = 4 waves; each wave owns 16 q-rows. Each LANE owns one q-row per MFMA:
//   S^T = mfma(K,Q): lane(lo,hi) holds S[q=lo][k=16n+4hi+rg] -> row softmax is in-lane
//   + 2 shuffles. P repacked to PV B-frag via 2KB wave-private LDS exchange (no barrier).
//   O^T = mfma(V^T,P): q stays lane-local -> scalar l-normalize.
// qkv: [8192][2048] bf16 (cols 0..1023 = Q(h,e) prescaled, 1024..2047 = K(h,e))
// vt:  [64][64][2048] bf16 (bh, e, s);  heads: [8192][1024] bf16 out
__global__ __launch_bounds__(256, 4) void attn_kernel(
    const u16* __restrict__ qkv, const u16* __restrict__ vt, u16* __restrict__ heads) {
  const int bx = blockIdx.x;   // 0..15
  const int bh = blockIdx.y;   // 0..63
  const int b = bh >> 4, h = bh & 15;
  const int tid = threadIdx.x;
  const int w = tid >> 6, lane = tid & 63, lo = lane & 15, hi = lane >> 4;

  __shared__ char lds[40960];
  char* sQP = lds;            // 8KB: Q [64][64] swz; after Q->regs, per-wave P exchange (2KB each)
  char* sK  = lds + 8192;     // 2 x 8KB  (K rows k, cols e)
  char* sV  = lds + 24576;    // 2 x 8KB  (V^T rows e, cols s)

  const u16* Kg = qkv + (size_t)(b * 2048) * 2048 + 1024 + h * 64;
  const u16* Vg = vt + (size_t)bh * 64 * 2048;

  auto stageKV = [&](int buf, int kv0) {
#pragma unroll
    for (int it = 0; it < 2; ++it) {
      const int L = (it * 4 + w) * 64 + lane;
      const int r = L >> 3, p = L & 7, c = p ^ (r & 7);
      gload_lds16(Kg + (size_t)(kv0 + r) * 2048 + c * 8, sK + buf * 8192 + (it * 4 + w) * 1024);
      gload_lds16(Vg + (size_t)r * 2048 + kv0 + c * 8, sV + buf * 8192 + (it * 4 + w) * 1024);
    }
  };

  char* sP = sQP + w * 2048;   // wave-private P exchange buffer

  for (int rep = 0; rep < 2; ++rep) {
    const int qt = rep ? (31 - bx) : bx;
    const u16* Qg = qkv + (size_t)(b * 2048 + qt * 64) * 2048 + h * 64;

    // stage Q tile [64][64]
#pragma unroll
    for (int it = 0; it < 2; ++it) {
      const int L = (it * 4 + w) * 64 + lane;
      const int r = L >> 3, p = L & 7, c = p ^ (r & 7);
      gload_lds16(Qg + (size_t)r * 2048 + c * 8, sQP + (it * 4 + w) * 1024);
    }
    stageKV(0, 0);
    __syncthreads();

    bf16x8 qf[2];   // B-frag: Q[q = w*16+lo][k = kc*32+hi*8 ..+7]
#pragma unroll
    for (int kc = 0; kc < 2; ++kc) {
      const int r = w * 16 + lo;
      const int p = (kc * 4 + hi) ^ (r & 7);
      qf[kc] = *reinterpret_cast<const bf16x8*>(sQP + r * 128 + p * 16);
    }
    __syncthreads();   // Q in regs; sQP region becomes P exchange space

    float mreg = -1e30f, lrow = 0.f;
    f32x4 oacc[4] = {};   // O^T: e = ne*16+hi*4+rg, q = lo (this wave's row w*16+lo)

    const int nt = qt + 1;
    int cur = 0;
    for (int t = 0; t < nt; ++t) {
      if (t + 1 < nt) stageKV(cur ^ 1, (t + 1) * 64);

      // S^T[k][q] = mfma(A=K rows k, B=Q rows q): sa[n][rg]: k = 16n+4hi+rg, q = w*16+lo
      f32x4 sa[4] = {};
#pragma unroll
      for (int kc = 0; kc < 2; ++kc) {
#pragma unroll
        for (int n = 0; n < 4; ++n) {
          const int r = n * 16 + lo;
          const int p = (kc * 4 + hi) ^ (r & 7);
          const bf16x8 kf = *reinterpret_cast<const bf16x8*>(sK + cur * 8192 + r * 128 + p * 16);
          sa[n] = __builtin_amdgcn_mfma_f32_16x16x32_bf16(kf, qf[kc], sa[n], 0, 0, 0);
        }
      }

      if (t == nt - 1) {   // diagonal tile: mask k_local > q_local (log2-domain big-neg)
        const int q = w * 16 + lo;
#pragma unroll
        for (int n = 0; n < 4; ++n)
#pragma unroll
          for (int rg = 0; rg < 4; ++rg)
            if (n * 16 + hi * 4 + rg > q) sa[n][rg] = -1e9f;
      }

      // in-register online softmax for row q=lo: in-lane max over 16 + 2 shuffles
      float pm = sa[0][0];
#pragma unroll
      for (int n = 0; n < 4; ++n)
#pragma unroll
        for (int rg = 0; rg < 4; ++rg) pm = fmaxf(pm, sa[n][rg]);
      pm = fmaxf(pm, __shfl_xor(pm, 16));
      pm = fmaxf(pm, __shfl_xor(pm, 32));
      if (!__all(pm <= mreg + 8.0f)) {      // defer-max (T13): rescale only when needed
        const float mn = fmaxf(mreg, pm);
        const float alpha = exp2f(mreg - mn);
        mreg = mn;
        lrow *= alpha;
#pragma unroll
        for (int ne = 0; ne < 4; ++ne)
#pragma unroll
          for (int rg = 0; rg < 4; ++rg) oacc[ne][rg] *= alpha;
      }
      float rs = 0.f;
#pragma unroll
      for (int n = 0; n < 4; ++n)
#pragma unroll
        for (int rg = 0; rg < 4; ++rg) {
          const float pv = exp2f(sa[n][rg] - mreg);
          sa[n][rg] = pv;
          rs += pv;
        }
      lrow += rs;   // per-lane partial (covers this lane's k-slice); reduced at epilogue

      // P -> PV B-frag layout via wave-private LDS exchange.
      // src (hi,n,rg): k=16n+4hi+rg  ->  dest lane hi'=2(n&1)+(hi>>1), kc=n>>1,
      // u32 slot j=2(hi&1)+(rg>>1), elem rg&1. XOR-swizzle col with dest hi.
#pragma unroll
      for (int n = 0; n < 4; ++n) {
        const unsigned w0 = cvt_pk_bf16(sa[n][0], sa[n][1]);
        const unsigned w1 = cvt_pk_bf16(sa[n][2], sa[n][3]);
        const int Hp = 2 * (n & 1) + (hi >> 1);
        *reinterpret_cast<uint2*>(sP + (n >> 1) * 1024 + Hp * 256 +
                                  ((lo ^ Hp) << 4) + ((hi & 1) << 3)) = uint2{w0, w1};
      }
      asm volatile("s_waitcnt lgkmcnt(0)" ::: "memory");   // in-wave write->read visibility
      bf16x8 pf[2];
#pragma unroll
      for (int kc = 0; kc < 2; ++kc)
        pf[kc] = *reinterpret_cast<const bf16x8*>(sP + kc * 1024 + hi * 256 + ((lo ^ hi) << 4));

      // O^T += mfma(A=V^T rows e, B=P rows q)
#pragma unroll
      for (int kc = 0; kc < 2; ++kc) {
#pragma unroll
        for (int ne = 0; ne < 4; ++ne) {
          const int r = ne * 16 + lo;
          const int p = (kc * 4 + hi) ^ (r & 7);
          const bf16x8 vf = *reinterpret_cast<const bf16x8*>(sV + cur * 8192 + r * 128 + p * 16);
          oacc[ne] = __builtin_amdgcn_mfma_f32_16x16x32_bf16(vf, pf[kc], oacc[ne], 0, 0, 0);
        }
      }
      __syncthreads();
      cur ^= 1;
    }

    // epilogue: full row-sum over hi groups, normalize, store 8B chunks
    float lsum = lrow;
    lsum += __shfl_xor(lsum, 16);
    lsum += __shfl_xor(lsum, 32);
    const float inv = 1.0f / lsum;
    const int q = qt * 64 + w * 16 + lo;
    u16* dst = heads + (size_t)(b * 2048 + q) * 1024 + h * 64;
#pragma unroll
    for (int ne = 0; ne < 4; ++ne) {   // e = ne*16 + hi*4 + rg
      const unsigned r0 = cvt_pk_bf16(oacc[ne][0] * inv, oacc[ne][1] * inv);
      const unsigned r1 = cvt_pk_bf16(oacc[ne][2] * inv, oacc[ne][3] * inv);
      *reinterpret_cast<uint2*>(dst + ne * 16 + hi * 4) = uint2{r0, r1};
    }
    // next rep: all waves passed the loop's final barrier; epilogue is reg/global-only,
    // so restaging sQP/sK/sV is race-free.
  }
}

extern "C" void kernel_launch(void* const* d_in, const int* in_sizes, int n_in,
                              void* d_out, int out_size, void* d_ws, size_t ws_size,
                              hipStream_t stream) {
  const float* x  = (const float*)d_in[0];
  const float* wq = (const float*)d_in[1];
  const float* wk = (const float*)d_in[2];
  const float* wv = (const float*)d_in[3];
  const float* wo = (const float*)d_in[4];

  char* ws = (char*)d_ws;
  u16* xb    = (u16*)(ws);                 // [8192][1024]      16.78 MB
  u16* wqkvb = (u16*)(ws + 16777216);      // [3072][1024]       6.29 MB
  u16* wob   = (u16*)(ws + 23068672);      // [1024][1024]       2.10 MB
  u16* qkv   = (u16*)(ws + 25165824);      // [8192][2048]      33.55 MB
  u16* vtp   = (u16*)(ws + 58720256);      // [64][64][2048]    16.78 MB
  u16* heads = (u16*)(ws + 75497472);      // [8192][1024]      16.78 MB
  // total 92.3 MB

  cast_kernel<<<8192, 256, 0, stream>>>(x, xb, 2097152);
  cast_w_kernel<<<dim3(1024, 4), 256, 0, stream>>>(wq, wk, wv, wo, wqkvb, wob);

  gemm_bt<1><<<dim3(24, 64), 256, 0, stream>>>(xb, wqkvb, qkv, vtp, 3072);
  attn_kernel<<<dim3(16, 64), 256, 0, stream>>>(qkv, vtp, heads);
  gemm_bt<0><<<dim3(8, 64), 256, 0, stream>>>(heads, wob, d_out, nullptr, 1024);
}